// Round 4
// baseline (403.089 us; speedup 1.0000x reference)
//
#include <hip/hip_runtime.h>

typedef __attribute__((ext_vector_type(8))) short bhalf8;
typedef __attribute__((ext_vector_type(4))) float floatx4;

#define NF 6  // freq_list = [1,103,205,307,409,511] -> periods [2,104,206,308,410,512]

__device__ __forceinline__ unsigned short f2bf(float f) {
  unsigned u = __float_as_uint(f);
  u += 0x7FFFu + ((u >> 16) & 1u);
  return (unsigned short)(u >> 16);
}

// ---------------- kernel 1: period weights (6-freq DFT + softmax) ----------
// 512 threads = 8 waves; wave w handles t in [w*128, w*128+128), lane = f.
// Per-freq complex rotation recurrence replaces per-t sincos.
__global__ __launch_bounds__(512) void pw_kernel(const float* __restrict__ x,
                                                 float* __restrict__ pwbuf) {
  const int bh = blockIdx.x;
  const int tid = threadIdx.x;
  const int w = tid >> 6;
  const int f = tid & 63;
  const int t0w = w * 128;
  const float* xb = x + (size_t)bh * 65536 + f;

  const float STEP = -6.283185307179586f / 1024.0f;
  float re[NF], im[NF], c[NF], s[NF], ck[NF], sk[NF];
#pragma unroll
  for (int k = 0; k < NF; ++k) {
    int freq = 1 + 102 * k;
    int ph0 = (freq * t0w) & 1023;
    __sincosf((float)ph0 * STEP, &s[k], &c[k]);
    __sincosf((float)freq * STEP, &sk[k], &ck[k]);
    re[k] = 0.f;
    im[k] = 0.f;
  }
#pragma unroll 4
  for (int t = 0; t < 128; ++t) {
    float v = xb[(size_t)(t0w + t) * 64];
#pragma unroll
    for (int k = 0; k < NF; ++k) {
      re[k] = fmaf(v, c[k], re[k]);
      im[k] = fmaf(v, s[k], im[k]);
      float cn = fmaf(c[k], ck[k], -s[k] * sk[k]);
      float sn = fmaf(c[k], sk[k], s[k] * ck[k]);
      c[k] = cn;
      s[k] = sn;
    }
  }
  __shared__ float part[8][NF][64][2];  // 24 KB
#pragma unroll
  for (int k = 0; k < NF; ++k) {
    part[w][k][f][0] = re[k];
    part[w][k][f][1] = im[k];
  }
  __syncthreads();
  if (tid < 64) {
    float sm[NF];
#pragma unroll
    for (int k = 0; k < NF; ++k) {
      float rr = 0.f, ii = 0.f;
#pragma unroll
      for (int ww = 0; ww < 8; ++ww) {
        rr += part[ww][k][tid][0];
        ii += part[ww][k][tid][1];
      }
      float amp = sqrtf(rr * rr + ii * ii);
#pragma unroll
      for (int off = 32; off > 0; off >>= 1) amp += __shfl_xor(amp, off);
      sm[k] = amp * (1.0f / 64.0f);
    }
    if (tid == 0) {
      float m = sm[0];
#pragma unroll
      for (int i = 1; i < NF; ++i) m = fmaxf(m, sm[i]);
      float e[NF], ssum = 0.f;
#pragma unroll
      for (int i = 0; i < NF; ++i) {
        e[i] = __expf(sm[i] - m);
        ssum += e[i];
      }
      float inv = 1.0f / ssum;
#pragma unroll
      for (int i = 0; i < NF; ++i) pwbuf[bh * NF + i] = e[i] * inv;
    }
  }
}

// ---------------- kernel 2: W -> plain transposed bf16 image ---------------
// wt_img[didj][fo][fi] = bf16(W[didj][fi][fo]); row fo = 128 B, no swizzle
// (read as 16B fragments straight from L2 by conv_kernel).
__global__ void prep_w(const float* __restrict__ W,
                       unsigned short* __restrict__ wt_img) {
  int task = blockIdx.x * 256 + threadIdx.x;  // 9*64*8 = 4608 tasks
  int didj = task >> 9;
  int fo = (task >> 3) & 63;
  int c = task & 7;
  bhalf8 pk;
#pragma unroll
  for (int j = 0; j < 8; ++j) {
    int fi = c * 8 + j;
    pk[j] = (short)f2bf(W[(size_t)(didj * 64 + fi) * 64 + fo]);
  }
  *(bhalf8*)((char*)wt_img + (size_t)didj * 8192 + fo * 128 + c * 16) = pk;
}

// ---------------- kernel 3: fused 6-period conv + relu + weighted sum + x --
// Stage-once / single-barrier design: 152-row near window covers all taps of
// kp>=1 (q<=10) and kp0's center di; one 132-row far strip covers kp0's valid
// off-center di (blocks never straddle t=512). B-fragments read directly from
// the L2-resident wt_img (no W LDS) -> 36.4 KB LDS -> 2 blocks/CU.
// didj outer (B-frags in regs, amortized over 6 periods), kp inner (unrolled,
// acc[6][2][4] static-indexed).
__global__ __launch_bounds__(256, 2) void conv_kernel(
    const float* __restrict__ x, const unsigned short* __restrict__ wt_img,
    const float* __restrict__ bias, const float* __restrict__ pwbuf,
    float* __restrict__ out) {
  __shared__ __align__(16) unsigned short win[152 * 64];   // 19456 B
  __shared__ __align__(16) unsigned short farw[132 * 64];  // 16896 B

  const int tid = threadIdx.x;
  const int bh = blockIdx.y;
  const int t0 = blockIdx.x * 128;
  const float* xbh = x + (size_t)bh * (1024 * 64);

  // ---- stage near window: row trel <-> t' = t0 - 12 + trel
  {
    const int fi0 = (tid & 7) * 8;
#pragma unroll
    for (int rr = 0; rr < 5; ++rr) {
      int trel = (tid >> 3) + rr * 32;
      if (trel < 152) {
        int tp = t0 - 12 + trel;
        float va[8];
        if ((unsigned)tp < 1024u) {
          const float4* src = (const float4*)(xbh + (size_t)tp * 64 + fi0);
          float4 u0 = src[0], u1 = src[1];
          va[0] = u0.x; va[1] = u0.y; va[2] = u0.z; va[3] = u0.w;
          va[4] = u1.x; va[5] = u1.y; va[6] = u1.z; va[7] = u1.w;
        } else {
#pragma unroll
          for (int j = 0; j < 8; ++j) va[j] = 0.f;
        }
        bhalf8 pk;
#pragma unroll
        for (int j = 0; j < 8; ++j) pk[j] = (short)f2bf(va[j]);
        *(bhalf8*)((char*)win + (trel << 7) +
                   ((fi0 * 2) ^ ((trel & 7) << 4))) = pk;
      }
    }
    // ---- stage far strip: row trel <-> t' = fb + trel
    const int fb = (t0 < 512) ? (t0 + 510) : (t0 - 514);
#pragma unroll
    for (int rr = 0; rr < 5; ++rr) {
      int trel = (tid >> 3) + rr * 32;
      if (trel < 132) {
        int tp = fb + trel;
        float va[8];
        if ((unsigned)tp < 1024u) {
          const float4* src = (const float4*)(xbh + (size_t)tp * 64 + fi0);
          float4 u0 = src[0], u1 = src[1];
          va[0] = u0.x; va[1] = u0.y; va[2] = u0.z; va[3] = u0.w;
          va[4] = u1.x; va[5] = u1.y; va[6] = u1.z; va[7] = u1.w;
        } else {
#pragma unroll
          for (int j = 0; j < 8; ++j) va[j] = 0.f;
        }
        bhalf8 pk;
#pragma unroll
        for (int j = 0; j < 8; ++j) pk[j] = (short)f2bf(va[j]);
        *(bhalf8*)((char*)farw + (trel << 7) +
                   ((fi0 * 2) ^ ((trel & 7) << 4))) = pk;
      }
    }
  }
  __syncthreads();  // the only barrier

  const int l15 = tid & 15;
  const int l4 = (tid >> 4) & 3;
  const int wid = tid >> 6;
  const int wm = wid * 32;
  const int vdi = (t0 < 512) ? 2 : 0;

  // per-(kp,mt) column coords for j'-validity masks (static-indexed)
  const int rt0 = t0 + wm + l15, rt1 = rt0 + 16;
  int jma[NF], jmb[NF];
  jma[0] = rt0 & 511;  jmb[0] = rt1 & 511;
  jma[1] = rt0 % 10;   jmb[1] = rt1 % 10;
  jma[2] = rt0 % 5;    jmb[2] = rt1 % 5;
  jma[3] = rt0 % 4;    jmb[3] = rt1 % 4;
  jma[4] = rt0 % 3;    jmb[4] = rt1 % 3;
  jma[5] = rt0 & 1;    jmb[5] = rt1 & 1;

  floatx4 acc[NF][2][4];
#pragma unroll
  for (int kp = 0; kp < NF; ++kp)
#pragma unroll
    for (int mt = 0; mt < 2; ++mt)
#pragma unroll
      for (int nt = 0; nt < 4; ++nt) acc[kp][mt][nt] = (floatx4)0.0f;

  const bhalf8 zz = (bhalf8)0;

#define DO_TAP(KP, BUF, R0, Q)                                                \
  {                                                                           \
    bool ok0 = (dj == 0) ? (jma[KP] > 0)                                      \
               : (dj == 2) ? (jma[KP] < (Q) - 1) : true;                      \
    bool ok1 = (dj == 0) ? (jmb[KP] > 0)                                      \
               : (dj == 2) ? (jmb[KP] < (Q) - 1) : true;                      \
    int r0_ = (R0), r1_ = r0_ + 16;                                           \
    _Pragma("unroll") for (int kk = 0; kk < 2; ++kk) {                        \
      int kb = kk * 64 + l4 * 16;                                             \
      bhalf8 a0 = *(const bhalf8*)((const char*)(BUF) + (r0_ << 7) +          \
                                   (kb ^ ((r0_ & 7) << 4)));                  \
      bhalf8 a1 = *(const bhalf8*)((const char*)(BUF) + (r1_ << 7) +          \
                                   (kb ^ ((r1_ & 7) << 4)));                  \
      if (!ok0) a0 = zz;                                                      \
      if (!ok1) a1 = zz;                                                      \
      _Pragma("unroll") for (int nt = 0; nt < 4; ++nt) {                      \
        acc[KP][0][nt] = __builtin_amdgcn_mfma_f32_16x16x32_bf16(             \
            a0, bfr[kk][nt], acc[KP][0][nt], 0, 0, 0);                        \
        acc[KP][1][nt] = __builtin_amdgcn_mfma_f32_16x16x32_bf16(             \
            a1, bfr[kk][nt], acc[KP][1][nt], 0, 0, 0);                        \
      }                                                                       \
    }                                                                         \
  }

#pragma unroll
  for (int di = 0; di < 3; ++di) {
#pragma unroll
    for (int dj = 0; dj < 3; ++dj) {
      // B-fragments for this tap straight from L2-resident wt_img,
      // reused by all 6 periods
      bhalf8 bfr[2][4];
      const char* wt = (const char*)wt_img + (size_t)(di * 3 + dj) * 8192;
#pragma unroll
      for (int kk = 0; kk < 2; ++kk)
#pragma unroll
        for (int nt = 0; nt < 4; ++nt) {
          int fo = nt * 16 + l15;
          bfr[kk][nt] =
              *(const bhalf8*)(wt + (fo << 7) + kk * 64 + l4 * 16);
        }
      const int base = wm + l15;
      // kp = 0 (q = 512): center di from win, valid far di from farw
      if (di == 1) {
        DO_TAP(0, win, base + 11 + dj, 512)
      } else if (di == vdi) {
        DO_TAP(0, farw, base + dj + 1, 512)
      }
      DO_TAP(1, win, base + 12 + (di - 1) * 10 + dj - 1, 10)
      DO_TAP(2, win, base + 12 + (di - 1) * 5 + dj - 1, 5)
      DO_TAP(3, win, base + 12 + (di - 1) * 4 + dj - 1, 4)
      DO_TAP(4, win, base + 12 + (di - 1) * 3 + dj - 1, 3)
      DO_TAP(5, win, base + 12 + (di - 1) * 2 + dj - 1, 2)
    }
  }
#undef DO_TAP

  // epilogue: out = sum_kp pw[kp]*relu(acc[kp]+b) + x
  float pwv[NF];
#pragma unroll
  for (int kp = 0; kp < NF; ++kp) pwv[kp] = pwbuf[bh * NF + kp];
  float bv[4];
#pragma unroll
  for (int nt = 0; nt < 4; ++nt) bv[nt] = bias[nt * 16 + l15];

#pragma unroll
  for (int mt = 0; mt < 2; ++mt) {
#pragma unroll
    for (int nt = 0; nt < 4; ++nt) {
      int row = t0 + wm + mt * 16 + l4 * 4;
      int col = nt * 16 + l15;
      size_t basep = ((size_t)bh * 1024 + row) * 64 + col;
#pragma unroll
      for (int r = 0; r < 4; ++r) {
        float y = 0.f;
#pragma unroll
        for (int kp = 0; kp < NF; ++kp)
          y = fmaf(pwv[kp], fmaxf(acc[kp][mt][nt][r] + bv[nt], 0.f), y);
        out[basep + (size_t)r * 64] = y + x[basep + (size_t)r * 64];
      }
    }
  }
}

extern "C" void kernel_launch(void* const* d_in, const int* in_sizes, int n_in,
                              void* d_out, int out_size, void* d_ws,
                              size_t ws_size, hipStream_t stream) {
  const float* x = (const float*)d_in[0];
  const float* W = (const float*)d_in[1];
  const float* b = (const float*)d_in[2];
  float* out = (float*)d_out;
  float* pwbuf = (float*)d_ws;                                    // 6144 B
  unsigned short* wt_img = (unsigned short*)((char*)d_ws + 8192); // 73728 B

  pw_kernel<<<dim3(256), dim3(512), 0, stream>>>(x, pwbuf);
  prep_w<<<dim3(18), dim3(256), 0, stream>>>(W, wt_img);
  conv_kernel<<<dim3(8, 256), dim3(256), 0, stream>>>(x, wt_img, b, pwbuf, out);
}

// Round 5
// 140.700 us; speedup vs baseline: 2.8649x; 2.8649x over previous
//
#include <hip/hip_runtime.h>

typedef __attribute__((ext_vector_type(8))) short bhalf8;
typedef __attribute__((ext_vector_type(4))) float floatx4;

#define NF 6  // freq_list = [1,103,205,307,409,511] -> periods [2,104,206,308,410,512]

__device__ __forceinline__ unsigned short f2bf(float f) {
  unsigned u = __float_as_uint(f);
  u += 0x7FFFu + ((u >> 16) & 1u);
  return (unsigned short)(u >> 16);
}

// ---------------- kernel 1: period weights (6-freq DFT + softmax) ----------
// 512 threads = 8 waves; wave w handles t in [w*128, w*128+128), lane = f.
__global__ __launch_bounds__(512) void pw_kernel(const float* __restrict__ x,
                                                 float* __restrict__ pwbuf) {
  const int bh = blockIdx.x;
  const int tid = threadIdx.x;
  const int w = tid >> 6;
  const int f = tid & 63;
  const int t0w = w * 128;
  const float* xb = x + (size_t)bh * 65536 + f;

  const float STEP = -6.283185307179586f / 1024.0f;
  float re[NF], im[NF], c[NF], s[NF], ck[NF], sk[NF];
#pragma unroll
  for (int k = 0; k < NF; ++k) {
    int freq = 1 + 102 * k;
    int ph0 = (freq * t0w) & 1023;
    __sincosf((float)ph0 * STEP, &s[k], &c[k]);
    __sincosf((float)freq * STEP, &sk[k], &ck[k]);
    re[k] = 0.f;
    im[k] = 0.f;
  }
#pragma unroll 4
  for (int t = 0; t < 128; ++t) {
    float v = xb[(size_t)(t0w + t) * 64];
#pragma unroll
    for (int k = 0; k < NF; ++k) {
      re[k] = fmaf(v, c[k], re[k]);
      im[k] = fmaf(v, s[k], im[k]);
      float cn = fmaf(c[k], ck[k], -s[k] * sk[k]);
      float sn = fmaf(c[k], sk[k], s[k] * ck[k]);
      c[k] = cn;
      s[k] = sn;
    }
  }
  __shared__ float part[8][NF][64][2];  // 24 KB
#pragma unroll
  for (int k = 0; k < NF; ++k) {
    part[w][k][f][0] = re[k];
    part[w][k][f][1] = im[k];
  }
  __syncthreads();
  if (tid < 64) {
    float sm[NF];
#pragma unroll
    for (int k = 0; k < NF; ++k) {
      float rr = 0.f, ii = 0.f;
#pragma unroll
      for (int ww = 0; ww < 8; ++ww) {
        rr += part[ww][k][tid][0];
        ii += part[ww][k][tid][1];
      }
      float amp = sqrtf(rr * rr + ii * ii);
#pragma unroll
      for (int off = 32; off > 0; off >>= 1) amp += __shfl_xor(amp, off);
      sm[k] = amp * (1.0f / 64.0f);
    }
    if (tid == 0) {
      float m = sm[0];
#pragma unroll
      for (int i = 1; i < NF; ++i) m = fmaxf(m, sm[i]);
      float e[NF], ssum = 0.f;
#pragma unroll
      for (int i = 0; i < NF; ++i) {
        e[i] = __expf(sm[i] - m);
        ssum += e[i];
      }
      float inv = 1.0f / ssum;
#pragma unroll
      for (int i = 0; i < NF; ++i) pwbuf[bh * NF + i] = e[i] * inv;
    }
  }
}

// ---------------- kernel 2: W -> transposed + pre-swizzled bf16 LDS image --
// wt_img[didj] is the exact 8KB LDS image: row fo (128B), phys chunk c (16B)
// holds Wt[fo][ (c ^ (fo&7))*8 .. +8 ] where Wt[fo][fi] = W[didj][fi][fo].
__global__ void prep_w(const float* __restrict__ W,
                       unsigned short* __restrict__ wt_img) {
  int task = blockIdx.x * 256 + threadIdx.x;  // 9*64*8 = 4608 tasks
  int didj = task >> 9;
  int fo = (task >> 3) & 63;
  int c = task & 7;
  int cs = c ^ (fo & 7);
  bhalf8 pk;
#pragma unroll
  for (int j = 0; j < 8; ++j) {
    int fi = cs * 8 + j;
    pk[j] = (short)f2bf(W[(size_t)(didj * 64 + fi) * 64 + fo]);
  }
  *(bhalf8*)((char*)wt_img + (size_t)didj * 8192 + fo * 128 + c * 16) = pk;
}

// ---------------- kernel 3: fused 6-period conv + relu + weighted sum + x --
// 512-thread blocks (8 waves = 2 waves/SIMD at 1 block/CU), wave tile
// 32 rows x 32 cols (wr = wid>>1, wc = wid&1) -> acc[6][2][2] = 96 VGPR,
// fits the 256-VGPR budget of 2 waves/SIMD without spilling.
// Stage-once / single-barrier: 152-row near window (all kp>=1 taps + kp0
// center di), 132-row far strip (kp0's valid off-center di; blocks never
// straddle t=512), all 9 swizzled W tiles. LDS = 110080 B.
__global__ __launch_bounds__(512, 2) void conv_kernel(
    const float* __restrict__ x, const unsigned short* __restrict__ wt_img,
    const float* __restrict__ bias, const float* __restrict__ pwbuf,
    float* __restrict__ out) {
  __shared__ __align__(16) unsigned short win[152 * 64];    // 19456 B
  __shared__ __align__(16) unsigned short farw[132 * 64];   // 16896 B
  __shared__ __align__(16) unsigned short wl[9 * 64 * 64];  // 73728 B

  const int tid = threadIdx.x;
  const int bh = blockIdx.y;
  const int t0 = blockIdx.x * 128;
  const float* xbh = x + (size_t)bh * (1024 * 64);

  // ---- stage near window: row trel <-> t' = t0 - 12 + trel
  {
    const int fi0 = (tid & 7) * 8;
#pragma unroll
    for (int rr = 0; rr < 3; ++rr) {
      int trel = (tid >> 3) + rr * 64;
      if (trel < 152) {
        int tp = t0 - 12 + trel;
        float va[8];
        if ((unsigned)tp < 1024u) {
          const float4* src = (const float4*)(xbh + (size_t)tp * 64 + fi0);
          float4 u0 = src[0], u1 = src[1];
          va[0] = u0.x; va[1] = u0.y; va[2] = u0.z; va[3] = u0.w;
          va[4] = u1.x; va[5] = u1.y; va[6] = u1.z; va[7] = u1.w;
        } else {
#pragma unroll
          for (int j = 0; j < 8; ++j) va[j] = 0.f;
        }
        bhalf8 pk;
#pragma unroll
        for (int j = 0; j < 8; ++j) pk[j] = (short)f2bf(va[j]);
        *(bhalf8*)((char*)win + (trel << 7) +
                   ((fi0 * 2) ^ ((trel & 7) << 4))) = pk;
      }
    }
    // ---- stage far strip: row trel <-> t' = fb + trel
    const int fb = (t0 < 512) ? (t0 + 510) : (t0 - 514);
#pragma unroll
    for (int rr = 0; rr < 3; ++rr) {
      int trel = (tid >> 3) + rr * 64;
      if (trel < 132) {
        int tp = fb + trel;
        float va[8];
        if ((unsigned)tp < 1024u) {
          const float4* src = (const float4*)(xbh + (size_t)tp * 64 + fi0);
          float4 u0 = src[0], u1 = src[1];
          va[0] = u0.x; va[1] = u0.y; va[2] = u0.z; va[3] = u0.w;
          va[4] = u1.x; va[5] = u1.y; va[6] = u1.z; va[7] = u1.w;
        } else {
#pragma unroll
          for (int j = 0; j < 8; ++j) va[j] = 0.f;
        }
        bhalf8 pk;
#pragma unroll
        for (int j = 0; j < 8; ++j) pk[j] = (short)f2bf(va[j]);
        *(bhalf8*)((char*)farw + (trel << 7) +
                   ((fi0 * 2) ^ ((trel & 7) << 4))) = pk;
      }
    }
    // ---- stage all 9 swizzled W tiles: 8192B/tile = 512 threads x 16B
#pragma unroll
    for (int d = 0; d < 9; ++d) {
      const char* src = (const char*)wt_img + (size_t)d * 8192;
      char* dst = (char*)wl + (size_t)d * 8192;
      *(bhalf8*)(dst + tid * 16) = *(const bhalf8*)(src + tid * 16);
    }
  }
  __syncthreads();  // the only barrier

  const int l15 = tid & 15;
  const int l4 = (tid >> 4) & 3;
  const int wid = tid >> 6;
  const int wm = (wid >> 1) * 32;  // wave row group
  const int wc = wid & 1;          // wave col group (fo half)
  const int vdi = (t0 < 512) ? 2 : 0;

  // per-(kp,mt) column coords for j'-validity masks (static-indexed)
  const int rt0 = t0 + wm + l15, rt1 = rt0 + 16;
  int jma[NF], jmb[NF];
  jma[0] = rt0 & 511;  jmb[0] = rt1 & 511;
  jma[1] = rt0 % 10;   jmb[1] = rt1 % 10;
  jma[2] = rt0 % 5;    jmb[2] = rt1 % 5;
  jma[3] = rt0 % 4;    jmb[3] = rt1 % 4;
  jma[4] = rt0 % 3;    jmb[4] = rt1 % 3;
  jma[5] = rt0 & 1;    jmb[5] = rt1 & 1;

  floatx4 acc[NF][2][2];
#pragma unroll
  for (int kp = 0; kp < NF; ++kp)
#pragma unroll
    for (int mt = 0; mt < 2; ++mt)
#pragma unroll
      for (int nt = 0; nt < 2; ++nt) acc[kp][mt][nt] = (floatx4)0.0f;

  const bhalf8 zz = (bhalf8)0;

#define DO_TAP(KP, BUF, R0, Q)                                                \
  {                                                                           \
    bool ok0 = (dj == 0) ? (jma[KP] > 0)                                      \
               : (dj == 2) ? (jma[KP] < (Q) - 1) : true;                      \
    bool ok1 = (dj == 0) ? (jmb[KP] > 0)                                      \
               : (dj == 2) ? (jmb[KP] < (Q) - 1) : true;                      \
    int r0_ = (R0), r1_ = r0_ + 16;                                           \
    _Pragma("unroll") for (int kk = 0; kk < 2; ++kk) {                        \
      int kb = kk * 64 + l4 * 16;                                             \
      bhalf8 a0 = *(const bhalf8*)((const char*)(BUF) + (r0_ << 7) +          \
                                   (kb ^ ((r0_ & 7) << 4)));                  \
      bhalf8 a1 = *(const bhalf8*)((const char*)(BUF) + (r1_ << 7) +          \
                                   (kb ^ ((r1_ & 7) << 4)));                  \
      if (!ok0) a0 = zz;                                                      \
      if (!ok1) a1 = zz;                                                      \
      _Pragma("unroll") for (int nt = 0; nt < 2; ++nt) {                      \
        acc[KP][0][nt] = __builtin_amdgcn_mfma_f32_16x16x32_bf16(             \
            a0, bfr[kk][nt], acc[KP][0][nt], 0, 0, 0);                        \
        acc[KP][1][nt] = __builtin_amdgcn_mfma_f32_16x16x32_bf16(             \
            a1, bfr[kk][nt], acc[KP][1][nt], 0, 0, 0);                        \
      }                                                                       \
    }                                                                         \
  }

#pragma unroll
  for (int di = 0; di < 3; ++di) {
#pragma unroll
    for (int dj = 0; dj < 3; ++dj) {
      // B-fragments for this tap (this wave's fo half), reused by 6 periods
      bhalf8 bfr[2][2];
      const char* wt = (const char*)wl + (size_t)(di * 3 + dj) * 8192;
#pragma unroll
      for (int kk = 0; kk < 2; ++kk)
#pragma unroll
        for (int nt = 0; nt < 2; ++nt) {
          int fo = wc * 32 + nt * 16 + l15;
          bfr[kk][nt] = *(const bhalf8*)(wt + (fo << 7) +
                                         ((kk * 64 + l4 * 16) ^
                                          ((fo & 7) << 4)));
        }
      const int base = wm + l15;
      // kp = 0 (q = 512): center di from win, valid far di from farw
      if (di == 1) {
        DO_TAP(0, win, base + 11 + dj, 512)
      } else if (di == vdi) {
        DO_TAP(0, farw, base + dj + 1, 512)
      }
      DO_TAP(1, win, base + 12 + (di - 1) * 10 + dj - 1, 10)
      DO_TAP(2, win, base + 12 + (di - 1) * 5 + dj - 1, 5)
      DO_TAP(3, win, base + 12 + (di - 1) * 4 + dj - 1, 4)
      DO_TAP(4, win, base + 12 + (di - 1) * 3 + dj - 1, 3)
      DO_TAP(5, win, base + 12 + (di - 1) * 2 + dj - 1, 2)
    }
  }
#undef DO_TAP

  // epilogue: out = sum_kp pw[kp]*relu(acc[kp]+b) + x
  float pwv[NF];
#pragma unroll
  for (int kp = 0; kp < NF; ++kp) pwv[kp] = pwbuf[bh * NF + kp];
  float bv[2];
#pragma unroll
  for (int nt = 0; nt < 2; ++nt) bv[nt] = bias[wc * 32 + nt * 16 + l15];

#pragma unroll
  for (int mt = 0; mt < 2; ++mt) {
#pragma unroll
    for (int nt = 0; nt < 2; ++nt) {
      int row = t0 + wm + mt * 16 + l4 * 4;
      int col = wc * 32 + nt * 16 + l15;
      size_t basep = ((size_t)bh * 1024 + row) * 64 + col;
#pragma unroll
      for (int r = 0; r < 4; ++r) {
        float y = 0.f;
#pragma unroll
        for (int kp = 0; kp < NF; ++kp)
          y = fmaf(pwv[kp], fmaxf(acc[kp][mt][nt][r] + bv[nt], 0.f), y);
        out[basep + (size_t)r * 64] = y + x[basep + (size_t)r * 64];
      }
    }
  }
}

extern "C" void kernel_launch(void* const* d_in, const int* in_sizes, int n_in,
                              void* d_out, int out_size, void* d_ws,
                              size_t ws_size, hipStream_t stream) {
  const float* x = (const float*)d_in[0];
  const float* W = (const float*)d_in[1];
  const float* b = (const float*)d_in[2];
  float* out = (float*)d_out;
  float* pwbuf = (float*)d_ws;                                    // 6144 B
  unsigned short* wt_img = (unsigned short*)((char*)d_ws + 8192); // 73728 B

  pw_kernel<<<dim3(256), dim3(512), 0, stream>>>(x, pwbuf);
  prep_w<<<dim3(18), dim3(256), 0, stream>>>(W, wt_img);
  conv_kernel<<<dim3(8, 256), dim3(512), 0, stream>>>(x, wt_img, b, pwbuf, out);
}